// Round 1
// baseline (4777.250 us; speedup 1.0000x reference)
//
#include <hip/hip_runtime.h>

#define BH  24
#define SEQ 4096
#define DIM 128
#define FF  256
#define CHK 128
#define NC  32
#define SLOT (FF*DIM)

typedef unsigned short u16;
typedef unsigned int   u32;

static __device__ __forceinline__ float bf2f(u16 u) {
    return __uint_as_float(((u32)u) << 16);
}
static __device__ __forceinline__ u16 f2bf(float f) {
    u32 u = __float_as_uint(f);
    u += 0x7fffu + ((u >> 16) & 1u);
    return (u16)(u >> 16);
}
static __device__ __forceinline__ void bf8_unpack(uint4 u, float o[8]) {
    o[0] = __uint_as_float(u.x << 16);
    o[1] = __uint_as_float(u.x & 0xffff0000u);
    o[2] = __uint_as_float(u.y << 16);
    o[3] = __uint_as_float(u.y & 0xffff0000u);
    o[4] = __uint_as_float(u.z << 16);
    o[5] = __uint_as_float(u.z & 0xffff0000u);
    o[6] = __uint_as_float(u.w << 16);
    o[7] = __uint_as_float(u.w & 0xffff0000u);
}

#define TTOK 32

// ---------------- phi: y = (silu(x@w1+b1))@w2 + b2, fp32 compute, bf16 out ----
__global__ __launch_bounds__(256) void phi_kernel(
    const float* __restrict__ xq, const float* __restrict__ xk,
    const float* __restrict__ w1, const float* __restrict__ b1,
    const float* __restrict__ w2, const float* __restrict__ b2,
    u16* __restrict__ yq, u16* __restrict__ yk)
{
    __shared__ float xs[TTOK*DIM];   // 16 KB
    __shared__ float hs[TTOK*FF];    // 32 KB
    const int tid = threadIdx.x;
    const int nTiles = (BH*SEQ)/TTOK;
    int b = blockIdx.x;
    const float* xin; u16* yout;
    if (b < nTiles) { xin = xq; yout = yq; }
    else            { xin = xk; yout = yk; b -= nTiles; }
    const size_t tok0 = (size_t)b * TTOK;

    for (int idx = tid; idx < TTOK*DIM; idx += 256)
        xs[idx] = xin[tok0*DIM + idx];
    __syncthreads();

    const float bb1 = b1[tid];
    for (int s = 0; s < TTOK/8; ++s) {
        float acc[8];
        #pragma unroll
        for (int t = 0; t < 8; ++t) acc[t] = bb1;
        for (int d4 = 0; d4 < DIM/4; ++d4) {
            float wa = w1[(d4*4+0)*FF + tid];
            float wb = w1[(d4*4+1)*FF + tid];
            float wc = w1[(d4*4+2)*FF + tid];
            float wd = w1[(d4*4+3)*FF + tid];
            #pragma unroll
            for (int t = 0; t < 8; ++t) {
                float4 xv = *reinterpret_cast<const float4*>(&xs[(s*8+t)*DIM + d4*4]);
                acc[t] += xv.x*wa + xv.y*wb + xv.z*wc + xv.w*wd;
            }
        }
        #pragma unroll
        for (int t = 0; t < 8; ++t) {
            float h = acc[t];
            float sg = 1.0f / (1.0f + __expf(-h));
            hs[(s*8+t)*FF + tid] = h * sg;
        }
    }
    __syncthreads();

    const float bb2 = b2[tid];
    for (int s = 0; s < TTOK/8; ++s) {
        float acc[8];
        #pragma unroll
        for (int t = 0; t < 8; ++t) acc[t] = bb2;
        for (int e4 = 0; e4 < FF/4; ++e4) {
            float wa = w2[(e4*4+0)*FF + tid];
            float wb = w2[(e4*4+1)*FF + tid];
            float wc = w2[(e4*4+2)*FF + tid];
            float wd = w2[(e4*4+3)*FF + tid];
            #pragma unroll
            for (int t = 0; t < 8; ++t) {
                float4 hv = *reinterpret_cast<const float4*>(&hs[(s*8+t)*FF + e4*4]);
                acc[t] += hv.x*wa + hv.y*wb + hv.z*wc + hv.w*wd;
            }
        }
        #pragma unroll
        for (int t = 0; t < 8; ++t)
            yout[(tok0 + s*8+t)*FF + tid] = f2bf(acc[t]);
    }
}

// ---------------- per-(head,chunk) KV sums -> states slot c+1 ----------------
__global__ __launch_bounds__(256) void kvsum_kernel(
    const u16* __restrict__ kphi, const float* __restrict__ v,
    float* __restrict__ states)
{
    __shared__ float vs[CHK*DIM];  // 64 KB
    const int c = blockIdx.x, h = blockIdx.y, tid = threadIdx.x;
    const size_t tok0 = (size_t)h*SEQ + (size_t)c*CHK;
    for (int idx = tid; idx < CHK*DIM; idx += 256)
        vs[idx] = v[tok0*DIM + idx];
    __syncthreads();
    const u16* kp = kphi + tok0*FF + tid;       // thread owns feature f=tid
    float* outp = states + ((size_t)h*(NC+1) + (size_t)(c+1))*SLOT + (size_t)tid*DIM;
    for (int db = 0; db < 4; ++db) {
        float acc[32];
        #pragma unroll
        for (int dd = 0; dd < 32; ++dd) acc[dd] = 0.f;
        for (int t = 0; t < CHK; ++t) {
            float kf = bf2f(kp[(size_t)t*FF]);
            #pragma unroll
            for (int d4 = 0; d4 < 8; ++d4) {
                float4 vv = *reinterpret_cast<const float4*>(&vs[t*DIM + db*32 + d4*4]);
                acc[d4*4+0] += kf*vv.x;
                acc[d4*4+1] += kf*vv.y;
                acc[d4*4+2] += kf*vv.z;
                acc[d4*4+3] += kf*vv.w;
            }
        }
        #pragma unroll
        for (int d4 = 0; d4 < 8; ++d4) {
            float4 o = make_float4(acc[d4*4], acc[d4*4+1], acc[d4*4+2], acc[d4*4+3]);
            *reinterpret_cast<float4*>(&outp[db*32 + d4*4]) = o;
        }
    }
}

// ---------------- per-head exclusive prefix over chunk sums ------------------
// After this: slot[c] = sum_{j<c} K_j  (slot 0 = 0, slot NC = total)
__global__ __launch_bounds__(256) void prefix_kernel(float* __restrict__ states)
{
    const int h = blockIdx.x, tid = threadIdx.x;
    float* base = states + (size_t)h*(NC+1)*SLOT;
    for (int e = tid*4; e < SLOT; e += 1024) {
        float4 run = make_float4(0.f,0.f,0.f,0.f);
        *reinterpret_cast<float4*>(&base[e]) = run;
        for (int c = 1; c <= NC; ++c) {
            float* p = &base[(size_t)c*SLOT + e];
            float4 kc = *reinterpret_cast<const float4*>(p);
            run.x += kc.x; run.y += kc.y; run.z += kc.z; run.w += kc.w;
            *reinterpret_cast<float4*>(p) = run;
        }
    }
}

// ---------------- output: scores + masked SV (both dirs) + inter states ------
__global__ __launch_bounds__(256) void out_kernel(
    const u16* __restrict__ qphi, const u16* __restrict__ kphi,
    const float* __restrict__ v, const float* __restrict__ states,
    float* __restrict__ out)
{
    __shared__ uint4 smem4[CHK*FF*2/16];           // 64 KB union
    u16*   ks = reinterpret_cast<u16*>(smem4);     // phase 1: K chunk bf16
    float* sT = reinterpret_cast<float*>(smem4);   // phase 2: scores transposed sT[j][i]
    const int c = blockIdx.x, h = blockIdx.y, tid = threadIdx.x;
    const size_t tok0 = (size_t)h*SEQ + (size_t)c*CHK;

    {
        const uint4* src = reinterpret_cast<const uint4*>(kphi + tok0*FF);
        for (int idx = tid; idx < CHK*FF/8; idx += 256)
            smem4[idx] = src[idx];
    }
    __syncthreads();

    const int i    = tid >> 1;
    const int half = tid & 1;
    const int j0   = half * 64;
    const uint4* qrow = reinterpret_cast<const uint4*>(qphi + (tok0 + (size_t)i)*FF);

    // phase 1: scores s[i][j] for j in [j0, j0+64), dot over F=256
    float acc[64];
    #pragma unroll
    for (int jj = 0; jj < 64; ++jj) acc[jj] = 0.f;
    const uint4* ks4 = reinterpret_cast<const uint4*>(ks);
    for (int f8 = 0; f8 < FF/8; ++f8) {
        float qv[8];
        bf8_unpack(qrow[f8], qv);
        #pragma unroll 8
        for (int jj = 0; jj < 64; ++jj) {
            float kv[8];
            bf8_unpack(ks4[(size_t)(j0+jj)*(FF/8) + f8], kv);
            acc[jj] += qv[0]*kv[0] + qv[1]*kv[1] + qv[2]*kv[2] + qv[3]*kv[3]
                     + qv[4]*kv[4] + qv[5]*kv[5] + qv[6]*kv[6] + qv[7]*kv[7];
        }
    }
    __syncthreads();          // everyone done reading ks
    #pragma unroll
    for (int jj = 0; jj < 64; ++jj)
        sT[(size_t)(j0+jj)*CHK + i] = acc[jj];
    __syncthreads();

    // phase 2: combine
    const int pos = c*CHK + i;
    const float invA = 1.0f / (float)(pos + 1);
    const float invB = 1.0f / (float)(SEQ - pos);
    const float* vbase = v + tok0*DIM;
    const float* stc = states + ((size_t)h*(NC+1) + (size_t)c)*SLOT;  // prefix (excl)
    const float* stn = stc + SLOT;                                    // prefix incl this chunk
    const float* stT = states + ((size_t)h*(NC+1) + (size_t)NC)*SLOT; // total
    float* orow = out + (tok0 + (size_t)i)*DIM;

    for (int dc = 0; dc < 2; ++dc) {
        const int dbase = half*64 + dc*32;
        float accA[32], accB[32];
        #pragma unroll
        for (int dd = 0; dd < 32; ++dd) { accA[dd]=0.f; accB[dd]=0.f; }

        // intra-chunk, both directions from same scores (shared rounding)
        for (int j = 0; j < CHK; ++j) {
            float s = sT[(size_t)j*CHK + i];
            const float4* vr = reinterpret_cast<const float4*>(vbase + (size_t)j*DIM + dbase);
            float4 vv[8];
            #pragma unroll
            for (int d4 = 0; d4 < 8; ++d4) vv[d4] = vr[d4];
            if (j <= i) {
                #pragma unroll
                for (int d4 = 0; d4 < 8; ++d4) {
                    accA[d4*4+0] += s*vv[d4].x; accA[d4*4+1] += s*vv[d4].y;
                    accA[d4*4+2] += s*vv[d4].z; accA[d4*4+3] += s*vv[d4].w;
                }
            }
            if (j >= i) {
                #pragma unroll
                for (int d4 = 0; d4 < 8; ++d4) {
                    accB[d4*4+0] += s*vv[d4].x; accB[d4*4+1] += s*vv[d4].y;
                    accB[d4*4+2] += s*vv[d4].z; accB[d4*4+3] += s*vv[d4].w;
                }
            }
        }

        // inter-chunk: A += q·prefix, B += q·(total - prefix_incl)
        for (int f8 = 0; f8 < FF/8; ++f8) {
            float qv[8];
            bf8_unpack(qrow[f8], qv);
            #pragma unroll 2
            for (int u = 0; u < 8; ++u) {
                const int f = f8*8 + u;
                const float4* a4 = reinterpret_cast<const float4*>(stc + (size_t)f*DIM + dbase);
                const float4* n4 = reinterpret_cast<const float4*>(stn + (size_t)f*DIM + dbase);
                const float4* t4 = reinterpret_cast<const float4*>(stT + (size_t)f*DIM + dbase);
                #pragma unroll
                for (int d4 = 0; d4 < 8; ++d4) {
                    float4 pa = a4[d4];
                    float4 nn = n4[d4];
                    float4 tt = t4[d4];
                    accA[d4*4+0] += qv[u]*pa.x;
                    accA[d4*4+1] += qv[u]*pa.y;
                    accA[d4*4+2] += qv[u]*pa.z;
                    accA[d4*4+3] += qv[u]*pa.w;
                    accB[d4*4+0] += qv[u]*(tt.x - nn.x);
                    accB[d4*4+1] += qv[u]*(tt.y - nn.y);
                    accB[d4*4+2] += qv[u]*(tt.z - nn.z);
                    accB[d4*4+3] += qv[u]*(tt.w - nn.w);
                }
            }
        }

        #pragma unroll
        for (int d4 = 0; d4 < 8; ++d4) {
            float4 o;
            o.x = accA[d4*4+0]*invA + accB[d4*4+0]*invB;
            o.y = accA[d4*4+1]*invA + accB[d4*4+1]*invB;
            o.z = accA[d4*4+2]*invA + accB[d4*4+2]*invB;
            o.w = accA[d4*4+3]*invA + accB[d4*4+3]*invB;
            *reinterpret_cast<float4*>(&orow[dbase + d4*4]) = o;
        }
    }
}

extern "C" void kernel_launch(void* const* d_in, const int* in_sizes, int n_in,
                              void* d_out, int out_size, void* d_ws, size_t ws_size,
                              hipStream_t stream) {
    const float* q  = (const float*)d_in[0];
    const float* k  = (const float*)d_in[1];
    const float* v  = (const float*)d_in[2];
    const float* w1 = (const float*)d_in[3];
    const float* b1 = (const float*)d_in[4];
    const float* w2 = (const float*)d_in[5];
    const float* b2 = (const float*)d_in[6];
    float* out = (float*)d_out;

    char* ws = (char*)d_ws;
    const size_t phiBytes = (size_t)BH*SEQ*FF*sizeof(u16);       // 50,331,648 B each
    u16* qphi = (u16*)ws;
    u16* kphi = (u16*)(ws + phiBytes);
    float* states = (float*)(ws + 2*phiBytes);                   // 24*33*32768*4 = 103,809,024 B
    // total ws usage ~195 MB

    phi_kernel<<<dim3(2*(BH*SEQ)/TTOK), 256, 0, stream>>>(q, k, w1, b1, w2, b2, qphi, kphi);
    kvsum_kernel<<<dim3(NC, BH), 256, 0, stream>>>(kphi, v, states);
    prefix_kernel<<<dim3(BH), 256, 0, stream>>>(states);
    out_kernel<<<dim3(NC, BH), 256, 0, stream>>>(qphi, kphi, v, states, out);
}

// Round 4
// 2502.716 us; speedup vs baseline: 1.9088x; 1.9088x over previous
//
#include <hip/hip_runtime.h>

#define BH  24
#define SEQ 4096
#define DIM 128
#define FF  256
#define CHK 128
#define NC  32
#define SLOT (FF*DIM)

typedef unsigned short u16;
typedef unsigned int   u32;
typedef short  s16x8 __attribute__((ext_vector_type(8)));
typedef float  f32x4 __attribute__((ext_vector_type(4)));

#define MFMA16(a,b,c) __builtin_amdgcn_mfma_f32_16x16x32_bf16(a,b,c,0,0,0)

static __device__ __forceinline__ float bf2f(u16 u) {
    return __uint_as_float(((u32)u) << 16);
}
static __device__ __forceinline__ u16 f2bf(float f) {
    u32 u = __float_as_uint(f);
    u += 0x7fffu + ((u >> 16) & 1u);
    return (u16)(u >> 16);
}
static __device__ __forceinline__ void bf8_unpack(uint4 u, float o[8]) {
    o[0] = __uint_as_float(u.x << 16);
    o[1] = __uint_as_float(u.x & 0xffff0000u);
    o[2] = __uint_as_float(u.y << 16);
    o[3] = __uint_as_float(u.y & 0xffff0000u);
    o[4] = __uint_as_float(u.z << 16);
    o[5] = __uint_as_float(u.z & 0xffff0000u);
    o[6] = __uint_as_float(u.w << 16);
    o[7] = __uint_as_float(u.w & 0xffff0000u);
}
static __device__ __forceinline__ void bf4_unpack(uint2 u, float o[4]) {
    o[0] = __uint_as_float(u.x << 16);
    o[1] = __uint_as_float(u.x & 0xffff0000u);
    o[2] = __uint_as_float(u.y << 16);
    o[3] = __uint_as_float(u.y & 0xffff0000u);
}

#define TTOK 32

// ---------------- phi: y = (silu(x@w1+b1))@w2 + b2  (proven R1) --------------
__global__ __launch_bounds__(256) void phi_kernel(
    const float* __restrict__ xq, const float* __restrict__ xk,
    const float* __restrict__ w1, const float* __restrict__ b1,
    const float* __restrict__ w2, const float* __restrict__ b2,
    u16* __restrict__ yq, u16* __restrict__ yk)
{
    __shared__ float xs[TTOK*DIM];
    __shared__ float hs[TTOK*FF];
    const int tid = threadIdx.x;
    const int nTiles = (BH*SEQ)/TTOK;
    int b = blockIdx.x;
    const float* xin; u16* yout;
    if (b < nTiles) { xin = xq; yout = yq; }
    else            { xin = xk; yout = yk; b -= nTiles; }
    const size_t tok0 = (size_t)b * TTOK;

    for (int idx = tid; idx < TTOK*DIM; idx += 256)
        xs[idx] = xin[tok0*DIM + idx];
    __syncthreads();

    const float bb1 = b1[tid];
    for (int s = 0; s < TTOK/8; ++s) {
        float acc[8];
        #pragma unroll
        for (int t = 0; t < 8; ++t) acc[t] = bb1;
        for (int d4 = 0; d4 < DIM/4; ++d4) {
            float wa = w1[(d4*4+0)*FF + tid];
            float wb = w1[(d4*4+1)*FF + tid];
            float wc = w1[(d4*4+2)*FF + tid];
            float wd = w1[(d4*4+3)*FF + tid];
            #pragma unroll
            for (int t = 0; t < 8; ++t) {
                float4 xv = *reinterpret_cast<const float4*>(&xs[(s*8+t)*DIM + d4*4]);
                acc[t] += xv.x*wa + xv.y*wb + xv.z*wc + xv.w*wd;
            }
        }
        #pragma unroll
        for (int t = 0; t < 8; ++t) {
            float h = acc[t];
            float sg = 1.0f / (1.0f + __expf(-h));
            hs[(s*8+t)*FF + tid] = h * sg;
        }
    }
    __syncthreads();

    const float bb2 = b2[tid];
    for (int s = 0; s < TTOK/8; ++s) {
        float acc[8];
        #pragma unroll
        for (int t = 0; t < 8; ++t) acc[t] = bb2;
        for (int e4 = 0; e4 < FF/4; ++e4) {
            float wa = w2[(e4*4+0)*FF + tid];
            float wb = w2[(e4*4+1)*FF + tid];
            float wc = w2[(e4*4+2)*FF + tid];
            float wd = w2[(e4*4+3)*FF + tid];
            #pragma unroll
            for (int t = 0; t < 8; ++t) {
                float4 hv = *reinterpret_cast<const float4*>(&hs[(s*8+t)*FF + e4*4]);
                acc[t] += hv.x*wa + hv.y*wb + hv.z*wc + hv.w*wd;
            }
        }
        #pragma unroll
        for (int t = 0; t < 8; ++t)
            yout[(tok0 + s*8+t)*FF + tid] = f2bf(acc[t]);
    }
}

// ------- per-(head,chunk) KV sums -> bf16 [f][d] (R1 structure, bf16 store) --
// chunkF[h][c][f][d] = sum_t kphi[t][f] * v[t][d]
__global__ __launch_bounds__(256) void kvsum_kernel(
    const u16* __restrict__ kphi, const float* __restrict__ v,
    u16* __restrict__ chunkF)
{
    __shared__ float vs[CHK*DIM];  // 64 KB
    const int c = blockIdx.x, h = blockIdx.y, tid = threadIdx.x;
    const size_t tok0 = (size_t)h*SEQ + (size_t)c*CHK;
    for (int idx = tid; idx < CHK*DIM; idx += 256)
        vs[idx] = v[tok0*DIM + idx];
    __syncthreads();
    const u16* kp = kphi + tok0*FF + tid;       // thread owns feature f=tid
    u16* outp = chunkF + ((size_t)(h*NC + c))*SLOT + (size_t)tid*DIM;
    for (int db = 0; db < 4; ++db) {
        float acc[32];
        #pragma unroll
        for (int dd = 0; dd < 32; ++dd) acc[dd] = 0.f;
        for (int t = 0; t < CHK; ++t) {
            float kf = bf2f(kp[(size_t)t*FF]);
            #pragma unroll
            for (int d4 = 0; d4 < 8; ++d4) {
                float4 vv = *reinterpret_cast<const float4*>(&vs[t*DIM + db*32 + d4*4]);
                acc[d4*4+0] += kf*vv.x;
                acc[d4*4+1] += kf*vv.y;
                acc[d4*4+2] += kf*vv.z;
                acc[d4*4+3] += kf*vv.w;
            }
        }
        #pragma unroll
        for (int d4 = 0; d4 < 8; ++d4) {
            u32 lo = (u32)f2bf(acc[d4*4+0]) | ((u32)f2bf(acc[d4*4+1]) << 16);
            u32 hi = (u32)f2bf(acc[d4*4+2]) | ((u32)f2bf(acc[d4*4+3]) << 16);
            *reinterpret_cast<uint2*>(outp + db*32 + d4*4) = make_uint2(lo, hi);
        }
    }
}

// ---------------- elementwise scan over chunks (layout-agnostic) -------------
// In-place: chunkF[c] -> exclusive prefix (becomes prefF).
// sufF[c] = total - inclusive_prefix[c]
__global__ __launch_bounds__(256) void scan_kernel(
    u16* __restrict__ chunkF, u16* __restrict__ sufF)
{
    const int g = blockIdx.x * 256 + threadIdx.x;   // 98304 threads
    const int h = g >> 12;                          // 4096 threads per head
    const int e = (g & 4095) * 8;
    u16* base  = chunkF + (size_t)h*NC*SLOT + e;
    u16* sbase = sufF   + (size_t)h*NC*SLOT + e;

    float tot[8];
    #pragma unroll
    for (int i = 0; i < 8; ++i) tot[i] = 0.f;
    for (int c = 0; c < NC; ++c) {
        uint4 r = *reinterpret_cast<const uint4*>(base + (size_t)c*SLOT);
        tot[0] += __uint_as_float(r.x << 16);
        tot[1] += __uint_as_float(r.x & 0xffff0000u);
        tot[2] += __uint_as_float(r.y << 16);
        tot[3] += __uint_as_float(r.y & 0xffff0000u);
        tot[4] += __uint_as_float(r.z << 16);
        tot[5] += __uint_as_float(r.z & 0xffff0000u);
        tot[6] += __uint_as_float(r.w << 16);
        tot[7] += __uint_as_float(r.w & 0xffff0000u);
    }
    float run[8];
    #pragma unroll
    for (int i = 0; i < 8; ++i) run[i] = 0.f;
    for (int c = 0; c < NC; ++c) {
        uint4 r = *reinterpret_cast<const uint4*>(base + (size_t)c*SLOT);
        float old[8];
        old[0] = __uint_as_float(r.x << 16);
        old[1] = __uint_as_float(r.x & 0xffff0000u);
        old[2] = __uint_as_float(r.y << 16);
        old[3] = __uint_as_float(r.y & 0xffff0000u);
        old[4] = __uint_as_float(r.z << 16);
        old[5] = __uint_as_float(r.z & 0xffff0000u);
        old[6] = __uint_as_float(r.w << 16);
        old[7] = __uint_as_float(r.w & 0xffff0000u);
        uint4 wp, wsuf;
        wp.x = (u32)f2bf(run[0]) | ((u32)f2bf(run[1]) << 16);
        wp.y = (u32)f2bf(run[2]) | ((u32)f2bf(run[3]) << 16);
        wp.z = (u32)f2bf(run[4]) | ((u32)f2bf(run[5]) << 16);
        wp.w = (u32)f2bf(run[6]) | ((u32)f2bf(run[7]) << 16);
        *reinterpret_cast<uint4*>(base + (size_t)c*SLOT) = wp;   // exclusive prefix
        #pragma unroll
        for (int i = 0; i < 8; ++i) run[i] += old[i];
        float sf[8];
        #pragma unroll
        for (int i = 0; i < 8; ++i) sf[i] = tot[i] - run[i];
        wsuf.x = (u32)f2bf(sf[0]) | ((u32)f2bf(sf[1]) << 16);
        wsuf.y = (u32)f2bf(sf[2]) | ((u32)f2bf(sf[3]) << 16);
        wsuf.z = (u32)f2bf(sf[4]) | ((u32)f2bf(sf[5]) << 16);
        wsuf.w = (u32)f2bf(sf[6]) | ((u32)f2bf(sf[7]) << 16);
        *reinterpret_cast<uint4*>(sbase + (size_t)c*SLOT) = wsuf;
    }
}

// ---------------- output kernel: MFMA scores + proven scalar phase-2 ---------
__global__ __launch_bounds__(256) void out_kernel(
    const u16* __restrict__ qphi, const u16* __restrict__ kphi,
    const float* __restrict__ v,
    const u16* __restrict__ prefF, const u16* __restrict__ sufF,
    float* __restrict__ out)
{
    __shared__ float sT[CHK*CHK];    // 64 KB, sT[j*CHK + i] = S[i][j]
    const int c = blockIdx.x, h = blockIdx.y;
    const int tid = threadIdx.x;
    const size_t tok0 = (size_t)h*SEQ + (size_t)c*CHK;
    const u16* qbase = qphi + tok0*FF;
    const u16* kbase = kphi + tok0*FF;

    // ---- phase 1: S = Qphi Kphi^T via MFMA, fp32 -> sT[j][i] ----
    {
        const int w = tid >> 6;
        const int lane = tid & 63;
        const int m = lane & 15;
        const int q = lane >> 4;
        const int rowA0 = (2*w)*16 + m, rowA1 = (2*w+1)*16 + m;
        f32x4 zero4 = {0.f, 0.f, 0.f, 0.f};
        f32x4 sacc[2][8];
        #pragma unroll
        for (int r = 0; r < 2; ++r)
            #pragma unroll
            for (int ct = 0; ct < 8; ++ct) sacc[r][ct] = zero4;

        for (int kk = 0; kk < 8; ++kk) {
            int ko = kk*32 + q*8;
            s16x8 a0 = *reinterpret_cast<const s16x8*>(qbase + (size_t)rowA0*FF + ko);
            s16x8 a1 = *reinterpret_cast<const s16x8*>(qbase + (size_t)rowA1*FF + ko);
            #pragma unroll
            for (int ct = 0; ct < 8; ++ct) {
                s16x8 b = *reinterpret_cast<const s16x8*>(kbase + (size_t)(ct*16 + m)*FF + ko);
                sacc[0][ct] = MFMA16(a0, b, sacc[0][ct]);
                sacc[1][ct] = MFMA16(a1, b, sacc[1][ct]);
            }
        }
        // C/D layout (m89-verified): col = lane&15, row = q*4 + reg
        #pragma unroll
        for (int r = 0; r < 2; ++r) {
            #pragma unroll
            for (int ct = 0; ct < 8; ++ct) {
                int col = ct*16 + m;              // K-token j
                #pragma unroll
                for (int reg = 0; reg < 4; ++reg) {
                    int row = (2*w + r)*16 + q*4 + reg;   // Q-token i
                    sT[col*CHK + row] = sacc[r][ct][reg];
                }
            }
        }
    }
    __syncthreads();

    // ---- phase 2: EXACT R1 proven scalar path (bf16 states, 2 streams) ----
    const int i    = tid >> 1;
    const int half = tid & 1;
    const uint4* qrow = reinterpret_cast<const uint4*>(qphi + (tok0 + (size_t)i)*FF);

    const int pos = c*CHK + i;
    const float invA = 1.0f / (float)(pos + 1);
    const float invB = 1.0f / (float)(SEQ - pos);
    const float* vbase = v + tok0*DIM;
    const u16* pf = prefF + (size_t)(h*NC + c)*SLOT;
    const u16* sf = sufF  + (size_t)(h*NC + c)*SLOT;
    float* orow = out + (tok0 + (size_t)i)*DIM;

    for (int dc = 0; dc < 2; ++dc) {
        const int dbase = half*64 + dc*32;
        float accA[32], accB[32];
        #pragma unroll
        for (int dd = 0; dd < 32; ++dd) { accA[dd]=0.f; accB[dd]=0.f; }

        // intra-chunk, both directions from same scores
        for (int j = 0; j < CHK; ++j) {
            float s = sT[(size_t)j*CHK + i];
            const float4* vr = reinterpret_cast<const float4*>(vbase + (size_t)j*DIM + dbase);
            float4 vv[8];
            #pragma unroll
            for (int d4 = 0; d4 < 8; ++d4) vv[d4] = vr[d4];
            if (j <= i) {
                #pragma unroll
                for (int d4 = 0; d4 < 8; ++d4) {
                    accA[d4*4+0] += s*vv[d4].x; accA[d4*4+1] += s*vv[d4].y;
                    accA[d4*4+2] += s*vv[d4].z; accA[d4*4+3] += s*vv[d4].w;
                }
            }
            if (j >= i) {
                #pragma unroll
                for (int d4 = 0; d4 < 8; ++d4) {
                    accB[d4*4+0] += s*vv[d4].x; accB[d4*4+1] += s*vv[d4].y;
                    accB[d4*4+2] += s*vv[d4].z; accB[d4*4+3] += s*vv[d4].w;
                }
            }
        }

        // inter-chunk: A += q·pref, B += q·suf  (bf16 states, [f][d])
        for (int f8 = 0; f8 < FF/8; ++f8) {
            float qv[8];
            bf8_unpack(qrow[f8], qv);
            #pragma unroll 2
            for (int u = 0; u < 8; ++u) {
                const int f = f8*8 + u;
                const uint2* p2 = reinterpret_cast<const uint2*>(pf + (size_t)f*DIM + dbase);
                const uint2* s2 = reinterpret_cast<const uint2*>(sf + (size_t)f*DIM + dbase);
                #pragma unroll
                for (int d8 = 0; d8 < 8; ++d8) {
                    float pv[4], sv[4];
                    bf4_unpack(p2[d8], pv);
                    bf4_unpack(s2[d8], sv);
                    #pragma unroll
                    for (int t = 0; t < 4; ++t) {
                        accA[d8*4+t] += qv[u]*pv[t];
                        accB[d8*4+t] += qv[u]*sv[t];
                    }
                }
            }
        }

        #pragma unroll
        for (int d4 = 0; d4 < 8; ++d4) {
            float4 o;
            o.x = accA[d4*4+0]*invA + accB[d4*4+0]*invB;
            o.y = accA[d4*4+1]*invA + accB[d4*4+1]*invB;
            o.z = accA[d4*4+2]*invA + accB[d4*4+2]*invB;
            o.w = accA[d4*4+3]*invA + accB[d4*4+3]*invB;
            *reinterpret_cast<float4*>(&orow[dbase + d4*4]) = o;
        }
    }
}

extern "C" void kernel_launch(void* const* d_in, const int* in_sizes, int n_in,
                              void* d_out, int out_size, void* d_ws, size_t ws_size,
                              hipStream_t stream) {
    const float* q  = (const float*)d_in[0];
    const float* k  = (const float*)d_in[1];
    const float* v  = (const float*)d_in[2];
    const float* w1 = (const float*)d_in[3];
    const float* b1 = (const float*)d_in[4];
    const float* w2 = (const float*)d_in[5];
    const float* b2 = (const float*)d_in[6];
    float* out = (float*)d_out;

    char* ws = (char*)d_ws;
    const size_t phiBytes = (size_t)BH*SEQ*FF*sizeof(u16);   // 50,331,648
    u16* qphi   = (u16*)ws;
    u16* kphi   = (u16*)(ws + phiBytes);
    u16* chunkF = (u16*)(ws + 2*phiBytes);   // becomes prefF in-place after scan
    u16* sufF   = (u16*)(ws + 3*phiBytes);
    // total ws usage = 4 * 50,331,648 = 201,326,592 B  (< 204,472,320 proven in R1)

    phi_kernel<<<dim3(2*(BH*SEQ)/TTOK), 256, 0, stream>>>(q, k, w1, b1, w2, b2, qphi, kphi);
    kvsum_kernel<<<dim3(NC, BH), 256, 0, stream>>>(kphi, v, chunkF);
    scan_kernel<<<dim3(384), 256, 0, stream>>>(chunkF, sufF);
    out_kernel<<<dim3(NC, BH), 256, 0, stream>>>(qphi, kphi, v, chunkF, sufF, out);
}

// Round 5
// 1908.719 us; speedup vs baseline: 2.5029x; 1.3112x over previous
//
#include <hip/hip_runtime.h>

#define BH  24
#define SEQ 4096
#define DIM 128
#define FF  256
#define CHK 128
#define NC  32
#define SLOT (FF*DIM)

typedef unsigned short u16;
typedef unsigned int   u32;
typedef short  s16x8 __attribute__((ext_vector_type(8)));
typedef float  f32x4 __attribute__((ext_vector_type(4)));

#define MFMA16(a,b,c) __builtin_amdgcn_mfma_f32_16x16x32_bf16(a,b,c,0,0,0)

static __device__ __forceinline__ float bf2f(u16 u) {
    return __uint_as_float(((u32)u) << 16);
}
static __device__ __forceinline__ u16 f2bf(float f) {
    u32 u = __float_as_uint(f);
    u += 0x7fffu + ((u >> 16) & 1u);
    return (u16)(u >> 16);
}

#define TTOK 32

// ---------------- phi: y = (silu(x@w1+b1))@w2 + b2  (proven R1) --------------
__global__ __launch_bounds__(256) void phi_kernel(
    const float* __restrict__ xq, const float* __restrict__ xk,
    const float* __restrict__ w1, const float* __restrict__ b1,
    const float* __restrict__ w2, const float* __restrict__ b2,
    u16* __restrict__ yq, u16* __restrict__ yk)
{
    __shared__ float xs[TTOK*DIM];
    __shared__ float hs[TTOK*FF];
    const int tid = threadIdx.x;
    const int nTiles = (BH*SEQ)/TTOK;
    int b = blockIdx.x;
    const float* xin; u16* yout;
    if (b < nTiles) { xin = xq; yout = yq; }
    else            { xin = xk; yout = yk; b -= nTiles; }
    const size_t tok0 = (size_t)b * TTOK;

    for (int idx = tid; idx < TTOK*DIM; idx += 256)
        xs[idx] = xin[tok0*DIM + idx];
    __syncthreads();

    const float bb1 = b1[tid];
    for (int s = 0; s < TTOK/8; ++s) {
        float acc[8];
        #pragma unroll
        for (int t = 0; t < 8; ++t) acc[t] = bb1;
        for (int d4 = 0; d4 < DIM/4; ++d4) {
            float wa = w1[(d4*4+0)*FF + tid];
            float wb = w1[(d4*4+1)*FF + tid];
            float wc = w1[(d4*4+2)*FF + tid];
            float wd = w1[(d4*4+3)*FF + tid];
            #pragma unroll
            for (int t = 0; t < 8; ++t) {
                float4 xv = *reinterpret_cast<const float4*>(&xs[(s*8+t)*DIM + d4*4]);
                acc[t] += xv.x*wa + xv.y*wb + xv.z*wc + xv.w*wd;
            }
        }
        #pragma unroll
        for (int t = 0; t < 8; ++t) {
            float h = acc[t];
            float sg = 1.0f / (1.0f + __expf(-h));
            hs[(s*8+t)*FF + tid] = h * sg;
        }
    }
    __syncthreads();

    const float bb2 = b2[tid];
    for (int s = 0; s < TTOK/8; ++s) {
        float acc[8];
        #pragma unroll
        for (int t = 0; t < 8; ++t) acc[t] = bb2;
        for (int e4 = 0; e4 < FF/4; ++e4) {
            float wa = w2[(e4*4+0)*FF + tid];
            float wb = w2[(e4*4+1)*FF + tid];
            float wc = w2[(e4*4+2)*FF + tid];
            float wd = w2[(e4*4+3)*FF + tid];
            #pragma unroll
            for (int t = 0; t < 8; ++t) {
                float4 hv = *reinterpret_cast<const float4*>(&hs[(s*8+t)*FF + e4*4]);
                acc[t] += hv.x*wa + hv.y*wb + hv.z*wc + hv.w*wd;
            }
        }
        #pragma unroll
        for (int t = 0; t < 8; ++t)
            yout[(tok0 + s*8+t)*FF + tid] = f2bf(acc[t]);
    }
}

// ------- per-(head,chunk) KV sums -> bf16 TRANSPOSED [d][f] (R3 producer) ----
// chunkT[h][c][d][f] = sum_t kphi[t][f] * v[t][d]
__global__ __launch_bounds__(256) void kvsum_kernel(
    const u16* __restrict__ kphi, const float* __restrict__ v,
    u16* __restrict__ chunkT)
{
    __shared__ u16 ks[CHK*FF];   // 64 KB bf16 kphi chunk
    const int c = blockIdx.x, h = blockIdx.y, tid = threadIdx.x;
    const size_t tok0 = (size_t)h*SEQ + (size_t)c*CHK;
    {
        const uint4* src = reinterpret_cast<const uint4*>(kphi + tok0*FF);
        uint4* dst = reinterpret_cast<uint4*>(ks);
        for (int i = tid; i < CHK*FF/8; i += 256) dst[i] = src[i];
    }
    __syncthreads();
    const int d  = tid & 127;
    const int fh = (tid >> 7) * 128;
    float acc[128];
    #pragma unroll
    for (int i = 0; i < 128; ++i) acc[i] = 0.f;
    for (int t = 0; t < CHK; ++t) {
        float vval = v[(tok0 + t)*DIM + d];
        const uint2* kr = reinterpret_cast<const uint2*>(ks + t*FF + fh);
        #pragma unroll
        for (int f4 = 0; f4 < 32; ++f4) {
            uint2 kk = kr[f4];
            acc[f4*4+0] += vval * __uint_as_float(kk.x << 16);
            acc[f4*4+1] += vval * __uint_as_float(kk.x & 0xffff0000u);
            acc[f4*4+2] += vval * __uint_as_float(kk.y << 16);
            acc[f4*4+3] += vval * __uint_as_float(kk.y & 0xffff0000u);
        }
    }
    u16* outp = chunkT + ((size_t)(h*NC + c))*SLOT + (size_t)d*FF + fh;
    #pragma unroll
    for (int f4 = 0; f4 < 32; ++f4) {
        u32 lo = (u32)f2bf(acc[f4*4+0]) | ((u32)f2bf(acc[f4*4+1]) << 16);
        u32 hi = (u32)f2bf(acc[f4*4+2]) | ((u32)f2bf(acc[f4*4+3]) << 16);
        *reinterpret_cast<uint2*>(outp + f4*4) = make_uint2(lo, hi);
    }
}

// ---------------- elementwise scan over chunks (layout-agnostic, proven) -----
__global__ __launch_bounds__(256) void scan_kernel(
    u16* __restrict__ chunkT, u16* __restrict__ sufT)
{
    const int g = blockIdx.x * 256 + threadIdx.x;
    const int h = g >> 12;
    const int e = (g & 4095) * 8;
    u16* base  = chunkT + (size_t)h*NC*SLOT + e;
    u16* sbase = sufT   + (size_t)h*NC*SLOT + e;

    float tot[8];
    #pragma unroll
    for (int i = 0; i < 8; ++i) tot[i] = 0.f;
    for (int c = 0; c < NC; ++c) {
        uint4 r = *reinterpret_cast<const uint4*>(base + (size_t)c*SLOT);
        tot[0] += __uint_as_float(r.x << 16);
        tot[1] += __uint_as_float(r.x & 0xffff0000u);
        tot[2] += __uint_as_float(r.y << 16);
        tot[3] += __uint_as_float(r.y & 0xffff0000u);
        tot[4] += __uint_as_float(r.z << 16);
        tot[5] += __uint_as_float(r.z & 0xffff0000u);
        tot[6] += __uint_as_float(r.w << 16);
        tot[7] += __uint_as_float(r.w & 0xffff0000u);
    }
    float run[8];
    #pragma unroll
    for (int i = 0; i < 8; ++i) run[i] = 0.f;
    for (int c = 0; c < NC; ++c) {
        uint4 r = *reinterpret_cast<const uint4*>(base + (size_t)c*SLOT);
        float old[8];
        old[0] = __uint_as_float(r.x << 16);
        old[1] = __uint_as_float(r.x & 0xffff0000u);
        old[2] = __uint_as_float(r.y << 16);
        old[3] = __uint_as_float(r.y & 0xffff0000u);
        old[4] = __uint_as_float(r.z << 16);
        old[5] = __uint_as_float(r.z & 0xffff0000u);
        old[6] = __uint_as_float(r.w << 16);
        old[7] = __uint_as_float(r.w & 0xffff0000u);
        uint4 wp, wsuf;
        wp.x = (u32)f2bf(run[0]) | ((u32)f2bf(run[1]) << 16);
        wp.y = (u32)f2bf(run[2]) | ((u32)f2bf(run[3]) << 16);
        wp.z = (u32)f2bf(run[4]) | ((u32)f2bf(run[5]) << 16);
        wp.w = (u32)f2bf(run[6]) | ((u32)f2bf(run[7]) << 16);
        *reinterpret_cast<uint4*>(base + (size_t)c*SLOT) = wp;
        #pragma unroll
        for (int i = 0; i < 8; ++i) run[i] += old[i];
        float sf[8];
        #pragma unroll
        for (int i = 0; i < 8; ++i) sf[i] = tot[i] - run[i];
        wsuf.x = (u32)f2bf(sf[0]) | ((u32)f2bf(sf[1]) << 16);
        wsuf.y = (u32)f2bf(sf[2]) | ((u32)f2bf(sf[3]) << 16);
        wsuf.z = (u32)f2bf(sf[4]) | ((u32)f2bf(sf[5]) << 16);
        wsuf.w = (u32)f2bf(sf[6]) | ((u32)f2bf(sf[7]) << 16);
        *reinterpret_cast<uint4*>(sbase + (size_t)c*SLOT) = wsuf;
    }
}

// ------- output: MFMA scores (proven) + scalar intra (proven) + MFMA inter ---
__global__ __launch_bounds__(256) void out_kernel(
    const u16* __restrict__ qphi, const u16* __restrict__ kphi,
    const float* __restrict__ v,
    const u16* __restrict__ prefT, const u16* __restrict__ sufT,
    float* __restrict__ out)
{
    __shared__ float sT[CHK*CHK];    // 64 KB: scores sT[j][i], then inter buffer
    const int c = blockIdx.x, h = blockIdx.y;
    const int tid = threadIdx.x;
    const int w = tid >> 6, lane = tid & 63;
    const int m = lane & 15, q = lane >> 4;
    const size_t tok0 = (size_t)h*SEQ + (size_t)c*CHK;
    const u16* qbase = qphi + tok0*FF;
    const u16* kbase = kphi + tok0*FF;
    const int rowA0 = (2*w)*16 + m, rowA1 = (2*w+1)*16 + m;
    f32x4 zero4 = {0.f, 0.f, 0.f, 0.f};

    // ---- phase 1: S = Qphi Kphi^T via MFMA, fp32 -> sT[j*CHK + i]  [R4] ----
    {
        f32x4 sacc[2][8];
        #pragma unroll
        for (int r = 0; r < 2; ++r)
            #pragma unroll
            for (int ct = 0; ct < 8; ++ct) sacc[r][ct] = zero4;

        for (int kk = 0; kk < 8; ++kk) {
            int ko = kk*32 + q*8;
            s16x8 a0 = *reinterpret_cast<const s16x8*>(qbase + (size_t)rowA0*FF + ko);
            s16x8 a1 = *reinterpret_cast<const s16x8*>(qbase + (size_t)rowA1*FF + ko);
            #pragma unroll
            for (int ct = 0; ct < 8; ++ct) {
                s16x8 b = *reinterpret_cast<const s16x8*>(kbase + (size_t)(ct*16 + m)*FF + ko);
                sacc[0][ct] = MFMA16(a0, b, sacc[0][ct]);
                sacc[1][ct] = MFMA16(a1, b, sacc[1][ct]);
            }
        }
        // C/D layout (HW-pinned in R4): col = lane&15, row = q*4 + reg
        #pragma unroll
        for (int r = 0; r < 2; ++r) {
            #pragma unroll
            for (int ct = 0; ct < 8; ++ct) {
                int col = ct*16 + m;
                #pragma unroll
                for (int reg = 0; reg < 4; ++reg) {
                    int row = (2*w + r)*16 + q*4 + reg;
                    sT[col*CHK + row] = sacc[r][ct][reg];
                }
            }
        }
    }
    __syncthreads();

    // ---- phase 2: scalar intra-chunk (R4-proven), both dc, accs in regs ----
    const int i    = tid >> 1;
    const int half = tid & 1;
    const float* vbase = v + tok0*DIM;
    float accA[2][32], accB[2][32];
    #pragma unroll
    for (int dc = 0; dc < 2; ++dc)
        #pragma unroll
        for (int t = 0; t < 32; ++t) { accA[dc][t] = 0.f; accB[dc][t] = 0.f; }

    for (int j = 0; j < CHK; ++j) {
        float s = sT[(size_t)j*CHK + i];
        bool fa = (j <= i), fb = (j >= i);
        #pragma unroll
        for (int dc = 0; dc < 2; ++dc) {
            const int dbase = half*64 + dc*32;
            const float4* vr = reinterpret_cast<const float4*>(vbase + (size_t)j*DIM + dbase);
            float4 vv[8];
            #pragma unroll
            for (int d4 = 0; d4 < 8; ++d4) vv[d4] = vr[d4];
            if (fa) {
                #pragma unroll
                for (int d4 = 0; d4 < 8; ++d4) {
                    accA[dc][d4*4+0] += s*vv[d4].x; accA[dc][d4*4+1] += s*vv[d4].y;
                    accA[dc][d4*4+2] += s*vv[d4].z; accA[dc][d4*4+3] += s*vv[d4].w;
                }
            }
            if (fb) {
                #pragma unroll
                for (int d4 = 0; d4 < 8; ++d4) {
                    accB[dc][d4*4+0] += s*vv[d4].x; accB[dc][d4*4+1] += s*vv[d4].y;
                    accB[dc][d4*4+2] += s*vv[d4].z; accB[dc][d4*4+3] += s*vv[d4].w;
                }
            }
        }
    }
    __syncthreads();   // sT (scores) dead

    // ---- phase 3: inter-chunk via MFMA; redistribute via rotated LDS --------
    // D[row=i][col=d] = sum_f Q[i][f] * state[f][d]; B from [d][f] layout.
    const u16* pf = prefT + (size_t)(h*NC + c)*SLOT;
    const u16* sf = sufT  + (size_t)(h*NC + c)*SLOT;
    #pragma unroll
    for (int stream = 0; stream < 2; ++stream) {
        const u16* st = (stream == 0) ? pf : sf;
        f32x4 cd[2][8];
        #pragma unroll
        for (int r = 0; r < 2; ++r)
            #pragma unroll
            for (int nt = 0; nt < 8; ++nt) cd[r][nt] = zero4;

        for (int kk = 0; kk < 8; ++kk) {
            int ko = kk*32 + q*8;
            s16x8 a0 = *reinterpret_cast<const s16x8*>(qbase + (size_t)rowA0*FF + ko);
            s16x8 a1 = *reinterpret_cast<const s16x8*>(qbase + (size_t)rowA1*FF + ko);
            #pragma unroll
            for (int nt = 0; nt < 8; ++nt) {
                s16x8 b = *reinterpret_cast<const s16x8*>(st + (size_t)(nt*16 + m)*FF + ko);
                cd[0][nt] = MFMA16(a0, b, cd[0][nt]);
                cd[1][nt] = MFMA16(a1, b, cd[1][nt]);
            }
        }
        // write D to LDS with +row rotation (conflict-free absorb reads)
        #pragma unroll
        for (int r = 0; r < 2; ++r) {
            #pragma unroll
            for (int nt = 0; nt < 8; ++nt) {
                int col = nt*16 + m;
                #pragma unroll
                for (int reg = 0; reg < 4; ++reg) {
                    int row = (2*w + r)*16 + q*4 + reg;
                    sT[row*CHK + ((col + row) & 127)] = cd[r][nt][reg];
                }
            }
        }
        __syncthreads();
        // absorb into scalar accs
        #pragma unroll
        for (int dc = 0; dc < 2; ++dc) {
            const int dbase = half*64 + dc*32;
            if (stream == 0) {
                #pragma unroll
                for (int t = 0; t < 32; ++t)
                    accA[dc][t] += sT[i*CHK + ((dbase + t + i) & 127)];
            } else {
                #pragma unroll
                for (int t = 0; t < 32; ++t)
                    accB[dc][t] += sT[i*CHK + ((dbase + t + i) & 127)];
            }
        }
        __syncthreads();
    }

    // ---- epilogue (R4-proven mapping) ----
    const int pos = c*CHK + i;
    const float ia = 1.0f / (float)(pos + 1);
    const float ib = 1.0f / (float)(SEQ - pos);
    float* orow = out + (tok0 + (size_t)i)*DIM;
    #pragma unroll
    for (int dc = 0; dc < 2; ++dc) {
        const int dbase = half*64 + dc*32;
        #pragma unroll
        for (int d4 = 0; d4 < 8; ++d4) {
            float4 o;
            o.x = accA[dc][d4*4+0]*ia + accB[dc][d4*4+0]*ib;
            o.y = accA[dc][d4*4+1]*ia + accB[dc][d4*4+1]*ib;
            o.z = accA[dc][d4*4+2]*ia + accB[dc][d4*4+2]*ib;
            o.w = accA[dc][d4*4+3]*ia + accB[dc][d4*4+3]*ib;
            *reinterpret_cast<float4*>(&orow[dbase + d4*4]) = o;
        }
    }
}

extern "C" void kernel_launch(void* const* d_in, const int* in_sizes, int n_in,
                              void* d_out, int out_size, void* d_ws, size_t ws_size,
                              hipStream_t stream) {
    const float* q  = (const float*)d_in[0];
    const float* k  = (const float*)d_in[1];
    const float* v  = (const float*)d_in[2];
    const float* w1 = (const float*)d_in[3];
    const float* b1 = (const float*)d_in[4];
    const float* w2 = (const float*)d_in[5];
    const float* b2 = (const float*)d_in[6];
    float* out = (float*)d_out;

    char* ws = (char*)d_ws;
    const size_t phiBytes = (size_t)BH*SEQ*FF*sizeof(u16);   // 50,331,648
    u16* qphi   = (u16*)ws;
    u16* kphi   = (u16*)(ws + phiBytes);
    u16* chunkT = (u16*)(ws + 2*phiBytes);   // becomes prefT in-place after scan
    u16* sufT   = (u16*)(ws + 3*phiBytes);
    // total ws = 201,326,592 B (< 204,472,320 proven)

    phi_kernel<<<dim3(2*(BH*SEQ)/TTOK), 256, 0, stream>>>(q, k, w1, b1, w2, b2, qphi, kphi);
    kvsum_kernel<<<dim3(NC, BH), 256, 0, stream>>>(kphi, v, chunkT);
    scan_kernel<<<dim3(384), 256, 0, stream>>>(chunkT, sufT);
    out_kernel<<<dim3(NC, BH), 256, 0, stream>>>(qphi, kphi, v, chunkT, sufT, out);
}